// Round 4
// baseline (236.547 us; speedup 1.0000x reference)
//
#include <hip/hip_runtime.h>
#include <math.h>

// Geometry: seg_out/logits (2,4,128,128,128) f32, y (2,1,128,128,128) i32,
// calib (20,4) f32, weight scalar int. Output: 1 f32 scalar.
#define VB 2097152            // voxels per (batch, channel) = 128^3
#define QB (VB / 4)           // float4 quads per (batch, channel)
#define NBINS 20

// ws words: [0..39] float acc[2][5][4] {Sp,Spt1,Cnt,St2,Spt2}x{ch};
//           [40..119] uint bins[2][2][20] {class1,class2}x{true,total}x{bin};
//           [120] uint block-completion counter.
#define WS_WORDS 121

// Privatized LDS histogram: 16 copies, stride 81 (odd => distinct banks per bin).
#define HCOPIES 16
#define HSTRIDE 81

#define NBLK 1024
#define BPB  512                      // blocks per batch
#define QSTRIDE (BPB * 256)           // 131072; KITER * QSTRIDE == QB
#define KITER 4

__device__ __forceinline__ float sel(const float4 v, int j) {
    return j == 0 ? v.x : (j == 1 ? v.y : (j == 2 ? v.z : v.w));
}
__device__ __forceinline__ int seli(const int4 v, int j) {
    return j == 0 ? v.x : (j == 1 ? v.y : (j == 2 ? v.z : v.w));
}
__device__ __forceinline__ float fsigmoid(float x) {
    return __fdividef(1.0f, 1.0f + __expf(-x));
}

__device__ double dice_term(const double Sp[2], const double St[2], const double Spt[2],
                            double w0, double w1)
{
    const double sumP = Sp[0] + Sp[1], sumT = St[0] + St[1];
    const double u1 = sumP + sumT;
    const double u0 = (2.0 * (double)VB - sumP) + (2.0 * (double)VB - sumT);
    const double uni = w0 * u0 + w1 * u1;
    double dsum = 0.0;
    for (int b = 0; b < 2; ++b) {
        const double i1 = Spt[b];
        const double i0 = (double)VB - Sp[b] - St[b] + Spt[b];
        const double inter = w0 * i0 + w1 * i1;
        double dice = (2.0 * inter + 1.0) / (uni + 1.0);
        if (isnan(dice)) dice = 1.0;
        dsum += dice;
    }
    return 1.0 - 0.5 * dsum;
}

__global__ void __launch_bounds__(256) hybrid_fused_k(
        const float* __restrict__ seg, const float* __restrict__ logits,
        const int* __restrict__ y, const int* __restrict__ wt,
        const float* __restrict__ calib,
        float* __restrict__ ws, float* __restrict__ out)
{
    const int b   = blockIdx.x & 1;       // interleave batches across XCDs
    const int blk = blockIdx.x >> 1;      // 0..511
    const int tid = threadIdx.x;

    __shared__ unsigned int shb[HCOPIES * HSTRIDE];   // 5184 B
    __shared__ float shred[20][4];
    __shared__ int last_flag;

    for (int i = tid; i < HCOPIES * HSTRIDE; i += 256) shb[i] = 0u;
    if (tid == 0) last_flag = 0;
    __syncthreads();

    // weight==1 => (1-w)*L2 == 0.0 exactly; skip the logits stream (uniform,
    // deterministic branch: inputs restored before every launch).
    const bool need2 = (wt[0] != 1);

    const float4* s0 = (const float4*)seg + (size_t)(b * 4 + 0) * QB;
    const float4* s1 = (const float4*)seg + (size_t)(b * 4 + 1) * QB;
    const float4* s2 = (const float4*)seg + (size_t)(b * 4 + 2) * QB;
    const float4* s3 = (const float4*)seg + (size_t)(b * 4 + 3) * QB;
    const int4*   yq = (const int4*)y + (size_t)b * QB;

    // acc: [0..3]=Sp, [4..7]=Spt1, [8..11]=St2, [12..15]=Spt2
    float acc[16];
    #pragma unroll
    for (int k = 0; k < 16; ++k) acc[k] = 0.0f;
    int cnt1 = 0, cnt2 = 0, cnt3 = 0;

    const float INV_STEP = 20.0f / (1.0f + 1e-8f);
    const int hbase = (tid & (HCOPIES - 1)) * HSTRIDE;
    const int q0 = blk * 256 + tid;

    // ---- software-pipelined main loop: prefetch k+1 while computing k ----
    float4 cP0 = s0[q0], cP1 = s1[q0], cP2 = s2[q0], cP3 = s3[q0];
    int4   cY  = yq[q0];

    #pragma unroll
    for (int k = 0; k < KITER; ++k) {
        float4 nP0, nP1, nP2, nP3; int4 nY;
        if (k + 1 < KITER) {
            const int q = q0 + (k + 1) * QSTRIDE;
            nP0 = s0[q]; nP1 = s1[q]; nP2 = s2[q]; nP3 = s3[q]; nY = yq[q];
        }
        float4 G0, G1, G2, G3;
        if (need2) {
            const float4* l0 = (const float4*)logits + (size_t)(b * 4 + 0) * QB;
            const float4* l1 = (const float4*)logits + (size_t)(b * 4 + 1) * QB;
            const float4* l2 = (const float4*)logits + (size_t)(b * 4 + 2) * QB;
            const float4* l3 = (const float4*)logits + (size_t)(b * 4 + 3) * QB;
            const int q = q0 + k * QSTRIDE;
            G0 = l0[q]; G1 = l1[q]; G2 = l2[q]; G3 = l3[q];
        }

        #pragma unroll
        for (int j = 0; j < 4; ++j) {
            const float pv0 = sel(cP0, j), pv1 = sel(cP1, j);
            const float pv2 = sel(cP2, j), pv3 = sel(cP3, j);
            const int yj = seli(cY, j);

            acc[0] += pv0; acc[1] += pv1; acc[2] += pv2; acc[3] += pv3;
            acc[4] += (yj == 0) ? pv0 : 0.0f;
            acc[5] += (yj == 1) ? pv1 : 0.0f;
            acc[6] += (yj == 2) ? pv2 : 0.0f;
            acc[7] += (yj == 3) ? pv3 : 0.0f;
            cnt1 += (yj == 1); cnt2 += (yj == 2); cnt3 += (yj == 3);

            if (need2) {
                const float sg0 = fsigmoid(sel(G0, j));
                const float sg1 = fsigmoid(sel(G1, j));
                const float sg2 = fsigmoid(sel(G2, j));
                const float sg3 = fsigmoid(sel(G3, j));
                acc[8]  += sg0; acc[9]  += sg1; acc[10] += sg2; acc[11] += sg3;
                acc[12] += pv0 * sg0; acc[13] += pv1 * sg1;
                acc[14] += pv2 * sg2; acc[15] += pv3 * sg3;
            }

            // softmax ratios; inputs in [0,1) so no max-subtraction needed.
            const float e0 = __expf(pv0), e1 = __expf(pv1);
            const float e2 = __expf(pv2), e3 = __expf(pv3);
            const float rinv = __frcp_rn((e0 + e1) + (e2 + e3));
            int b1 = (int)(e1 * rinv * INV_STEP); b1 = min(b1, 19);
            int b2 = (int)(e2 * rinv * INV_STEP); b2 = min(b2, 19);
            atomicAdd(&shb[hbase + 20 + b1], 1u);   // class-1 total
            atomicAdd(&shb[hbase + 60 + b2], 1u);   // class-2 total
            if (yj == 1 || yj == 2) {               // mutually exclusive trues
                const int addr = (yj == 1) ? (hbase + b1) : (hbase + 40 + b2);
                atomicAdd(&shb[addr], 1u);
            }
        }
        cP0 = nP0; cP1 = nP1; cP2 = nP2; cP3 = nP3; cY = nY;
    }

    // ---- block reduction ----
    // cnt1,cnt2 packed (wave totals <= 1024 < 65536 each); cnt3 separate.
    int p12 = cnt1 | (cnt2 << 16), p3 = cnt3;
    #pragma unroll
    for (int off = 32; off > 0; off >>= 1) {
        p12 += __shfl_xor(p12, off, 64);
        p3  += __shfl_xor(p3,  off, 64);
    }
    const int nacc = need2 ? 16 : 8;
    if (need2) {
        #pragma unroll
        for (int k = 0; k < 16; ++k) {
            float v = acc[k];
            #pragma unroll
            for (int off = 32; off > 0; off >>= 1) v += __shfl_xor(v, off, 64);
            acc[k] = v;
        }
    } else {
        #pragma unroll
        for (int k = 0; k < 8; ++k) {
            float v = acc[k];
            #pragma unroll
            for (int off = 32; off > 0; off >>= 1) v += __shfl_xor(v, off, 64);
            acc[k] = v;
        }
    }
    const int wave = tid >> 6, lane = tid & 63;
    if (lane == 0) {
        #pragma unroll
        for (int k = 0; k < 8; ++k) shred[k][wave] = acc[k];
        const float c1 = (float)(p12 & 0xffff), c2 = (float)(p12 >> 16), c3 = (float)p3;
        shred[8][wave]  = 64.0f * 4.0f * KITER - c1 - c2 - c3;   // cnt0
        shred[9][wave]  = c1; shred[10][wave] = c2; shred[11][wave] = c3;
        if (need2) {
            #pragma unroll
            for (int k = 8; k < 16; ++k) shred[k + 4][wave] = acc[k];
        }
    }
    __syncthreads();
    const int nrows = need2 ? 20 : 12;
    if (tid < nrows) {
        float t = shred[tid][0] + shred[tid][1] + shred[tid][2] + shred[tid][3];
        atomicAdd(&ws[b * 20 + tid], t);
    }
    if (tid < 80) {
        unsigned int v = 0;
        #pragma unroll
        for (int c = 0; c < HCOPIES; ++c) v += shb[c * HSTRIDE + tid];
        if (v) atomicAdd((unsigned int*)ws + 40 + tid, v);
    }
    __syncthreads();   // drains the ws atomics (vmcnt(0) before s_barrier)

    // ---- last-block-done: the final block runs the finalize ----
    if (tid == 0) {
        __threadfence();
        unsigned int* cnt = (unsigned int*)ws + 120;
        unsigned int old = __hip_atomic_fetch_add(cnt, 1u, __ATOMIC_ACQ_REL,
                                                  __HIP_MEMORY_SCOPE_AGENT);
        last_flag = (old == NBLK - 1);
    }
    __syncthreads();
    if (!last_flag || tid >= 64) return;
    __threadfence();

    const int t = tid;
    // ECE: lanes 0..39 each handle one (class, bin) cell.
    const unsigned int* bins = (const unsigned int*)ws + 40;
    float term = 0.0f;
    if (t < 40) {
        const int cc = t / NBINS, k = t % NBINS;
        const unsigned int nt = __hip_atomic_load(&bins[cc * 40 + k],
                                  __ATOMIC_RELAXED, __HIP_MEMORY_SCOPE_AGENT);
        const unsigned int nn = __hip_atomic_load(&bins[cc * 40 + 20 + k],
                                  __ATOMIC_RELAXED, __HIP_MEMORY_SCOPE_AGENT);
        const float bt   = fsigmoid((float)nt);
        const float btot = fsigmoid((float)nn);
        const float cal  = fsigmoid(calib[k * 4 + (cc + 1)]);
        const float d = cal - __fdividef(bt, btot);
        term = d * d;
    }
    #pragma unroll
    for (int off = 32; off > 0; off >>= 1) term += __shfl_xor(term, off, 64);

    if (t == 0) {
        float wsv[40];
        #pragma unroll
        for (int i = 0; i < 40; ++i)
            wsv[i] = __hip_atomic_load(&ws[i], __ATOMIC_RELAXED,
                                       __HIP_MEMORY_SCOPE_AGENT);
        const double means[4] = {0.03, 0.02, 0.01, 0.01};
        double L1 = 0.0, L2 = 0.0;
        for (int c = 0; c < 4; ++c) {
            const double mean = means[c];
            const double w1 = 1.0 / (mean * mean);
            const double w0 = 1.0 / ((1.0 - mean) * (1.0 - mean));
            double Sp[2], Spt1[2], C1[2], St2[2], Spt2[2];
            for (int bb = 0; bb < 2; ++bb) {
                Sp[bb]   = (double)wsv[bb * 20 + 0 + c];
                Spt1[bb] = (double)wsv[bb * 20 + 4 + c];
                C1[bb]   = (double)wsv[bb * 20 + 8 + c];
                St2[bb]  = (double)wsv[bb * 20 + 12 + c];
                Spt2[bb] = (double)wsv[bb * 20 + 16 + c];
            }
            L1 += dice_term(Sp, C1, Spt1, w0, w1);
            L2 += dice_term(Sp, St2, Spt2, w0, w1);
        }
        L1 *= 0.2; L2 *= 0.2;   // sum of 4 channel losses / 5.0
        const double w = (double)wt[0];
        const double ece = (double)term / (double)NBINS;
        out[0] = (float)(w * L1 + (1.0 - w) * L2 + ece);
    }
}

extern "C" void kernel_launch(void* const* d_in, const int* in_sizes, int n_in,
                              void* d_out, int out_size, void* d_ws, size_t ws_size,
                              hipStream_t stream)
{
    const float* seg    = (const float*)d_in[0];
    const float* calib  = (const float*)d_in[1];
    const float* logits = (const float*)d_in[2];
    const int*   y      = (const int*)d_in[3];
    const int*   wt     = (const int*)d_in[4];
    float* ws  = (float*)d_ws;
    float* out = (float*)d_out;

    hipMemsetAsync(ws, 0, WS_WORDS * sizeof(float), stream);
    hipLaunchKernelGGL(hybrid_fused_k, dim3(NBLK), dim3(256), 0, stream,
                       seg, logits, y, wt, calib, ws, out);
}

// Round 5
// 173.887 us; speedup vs baseline: 1.3604x; 1.3604x over previous
//
#include <hip/hip_runtime.h>
#include <math.h>

// Geometry: seg_out/logits (2,4,128,128,128) f32, y (2,1,128,128,128) i32,
// calib (20,4) f32, weight scalar int. Output: 1 f32 scalar.
#define VB 2097152            // voxels per (batch, channel) = 128^3
#define QB (VB / 4)           // float4 quads per (batch, channel)
#define NBINS 20

// ws words: [0..39] float acc[2][5][4] {Sp,Spt1,Cnt,St2,Spt2}x{ch};
//           [40..119] uint bins[2][2][20] {cls1,cls2}x{true,total}x{bin}
#define WS_WORDS 120

// Privatized LDS histogram: 8 copies, stride 81 words (81%32=17, odd =>
// for a fixed bin the copies sit on distinct banks). copy = tid&7 =>
// 8 lanes/copy per wave; with ~6 hot bins => ~1.5-way same-address.
#define HCOPIES 8
#define HSTRIDE 81

__device__ __forceinline__ float sel(const float4 v, int j) {
    return j == 0 ? v.x : (j == 1 ? v.y : (j == 2 ? v.z : v.w));
}
__device__ __forceinline__ int seli(const int4 v, int j) {
    return j == 0 ? v.x : (j == 1 ? v.y : (j == 2 ? v.z : v.w));
}

__global__ __launch_bounds__(256) void hybrid_main_k(
        const float* __restrict__ seg, const float* __restrict__ logits,
        const int* __restrict__ y, const int* __restrict__ wt,
        float* __restrict__ ws)
{
    const int b   = blockIdx.x & 1;       // interleave batches across XCDs
    const int blk = blockIdx.x >> 1;      // 0..511
    const int tid = threadIdx.x;

    __shared__ unsigned int shb[HCOPIES * HSTRIDE];   // 2592 B
    __shared__ float shred[20][4];

    for (int i = tid; i < HCOPIES * HSTRIDE; i += 256) shb[i] = 0u;
    __syncthreads();

    // weight==1 => (1-w)*L2 == 0 exactly; skip the logits stream (uniform,
    // deterministic branch: inputs restored before every launch).
    const bool need2 = (wt[0] != 1);

    const float4* s0 = (const float4*)seg + (size_t)(b * 4 + 0) * QB;
    const float4* s1 = (const float4*)seg + (size_t)(b * 4 + 1) * QB;
    const float4* s2 = (const float4*)seg + (size_t)(b * 4 + 2) * QB;
    const float4* s3 = (const float4*)seg + (size_t)(b * 4 + 3) * QB;
    const float4* l0 = (const float4*)logits + (size_t)(b * 4 + 0) * QB;
    const float4* l1 = (const float4*)logits + (size_t)(b * 4 + 1) * QB;
    const float4* l2 = (const float4*)logits + (size_t)(b * 4 + 2) * QB;
    const float4* l3 = (const float4*)logits + (size_t)(b * 4 + 3) * QB;
    const int4*   yq = (const int4*)y + (size_t)b * QB;

    // acc[0..3]=Sp, [4..7]=Spt1(one-hot), [8..11]=Cnt1(as float, exact),
    // [12..15]=St2(sigmoid), [16..19]=Spt2
    float acc[20];
    #pragma unroll
    for (int k = 0; k < 20; ++k) acc[k] = 0.0f;

    const float INV_STEP = 20.0f / (1.0f + 1e-8f);  // searchsorted(linspace(0,1+1e-8,21),'right')-1
    const int hbase = (tid & (HCOPIES - 1)) * HSTRIDE;

    for (int q = blk * 256 + tid; q < QB; q += 512 * 256) {
        const int4   yv = yq[q];
        const float4 p0 = s0[q], p1 = s1[q], p2 = s2[q], p3 = s3[q];
        float4 g0 = {0,0,0,0}, g1 = {0,0,0,0}, g2 = {0,0,0,0}, g3 = {0,0,0,0};
        if (need2) { g0 = l0[q]; g1 = l1[q]; g2 = l2[q]; g3 = l3[q]; }

        #pragma unroll
        for (int j = 0; j < 4; ++j) {
            const float pv0 = sel(p0, j), pv1 = sel(p1, j), pv2 = sel(p2, j), pv3 = sel(p3, j);
            const int yj = seli(yv, j);

            acc[0] += pv0; acc[1] += pv1; acc[2] += pv2; acc[3] += pv3;
            acc[4] += (yj == 0) ? pv0 : 0.0f;
            acc[5] += (yj == 1) ? pv1 : 0.0f;
            acc[6] += (yj == 2) ? pv2 : 0.0f;
            acc[7] += (yj == 3) ? pv3 : 0.0f;
            acc[8]  += (yj == 0) ? 1.0f : 0.0f;
            acc[9]  += (yj == 1) ? 1.0f : 0.0f;
            acc[10] += (yj == 2) ? 1.0f : 0.0f;
            acc[11] += (yj == 3) ? 1.0f : 0.0f;

            if (need2) {
                const float sg0 = __fdividef(1.0f, 1.0f + __expf(-sel(g0, j)));
                const float sg1 = __fdividef(1.0f, 1.0f + __expf(-sel(g1, j)));
                const float sg2 = __fdividef(1.0f, 1.0f + __expf(-sel(g2, j)));
                const float sg3 = __fdividef(1.0f, 1.0f + __expf(-sel(g3, j)));
                acc[12] += sg0; acc[13] += sg1; acc[14] += sg2; acc[15] += sg3;
                acc[16] += pv0 * sg0; acc[17] += pv1 * sg1;
                acc[18] += pv2 * sg2; acc[19] += pv3 * sg3;
            }

            // softmax over channels (matches jax.nn.softmax: exp(x - max)/sum)
            const float mx = fmaxf(fmaxf(pv0, pv1), fmaxf(pv2, pv3));
            const float e0 = __expf(pv0 - mx), e1 = __expf(pv1 - mx);
            const float e2 = __expf(pv2 - mx), e3 = __expf(pv3 - mx);
            const float ssum = (e0 + e1) + (e2 + e3);
            const float pr1 = __fdividef(e1, ssum);
            const float pr2 = __fdividef(e2, ssum);
            int b1 = (int)(pr1 * INV_STEP); if (b1 > 19) b1 = 19;
            int b2 = (int)(pr2 * INV_STEP); if (b2 > 19) b2 = 19;
            atomicAdd(&shb[hbase + 20 + b1], 1u);   // class-1 total
            atomicAdd(&shb[hbase + 60 + b2], 1u);   // class-2 total
            // class-1 true (yj==1) and class-2 true (yj==2) are mutually
            // exclusive -> one predicated atomic.
            if (yj == 1 || yj == 2) {
                const int addr = (yj == 1) ? (hbase + b1) : (hbase + 40 + b2);
                atomicAdd(&shb[addr], 1u);
            }
        }
    }

    // wave(64) shuffle reduce each of the 20 accumulators
    #pragma unroll
    for (int k = 0; k < 20; ++k) {
        float v = acc[k];
        #pragma unroll
        for (int off = 32; off > 0; off >>= 1) v += __shfl_xor(v, off, 64);
        acc[k] = v;
    }
    const int wave = tid >> 6, lane = tid & 63;
    if (lane == 0) {
        #pragma unroll
        for (int k = 0; k < 20; ++k) shred[k][wave] = acc[k];
    }
    __syncthreads();
    if (tid < 20) {
        float t = shred[tid][0] + shred[tid][1] + shred[tid][2] + shred[tid][3];
        atomicAdd(&ws[b * 20 + tid], t);
    }
    if (tid < 80) {
        unsigned int v = 0;
        #pragma unroll
        for (int c = 0; c < HCOPIES; ++c) v += shb[c * HSTRIDE + tid];
        if (v) atomicAdd((unsigned int*)ws + 40 + tid, v);
    }
}

__device__ __forceinline__ float fsigmoid(float x) {
    return __fdividef(1.0f, 1.0f + __expf(-x));
}

__device__ double dice_term(const double Sp[2], const double St[2], const double Spt[2],
                            double w0, double w1)
{
    const double sumP = Sp[0] + Sp[1], sumT = St[0] + St[1];
    const double u1 = sumP + sumT;
    const double u0 = (2.0 * (double)VB - sumP) + (2.0 * (double)VB - sumT);
    const double uni = w0 * u0 + w1 * u1;
    double dsum = 0.0;
    for (int b = 0; b < 2; ++b) {
        const double i1 = Spt[b];
        const double i0 = (double)VB - Sp[b] - St[b] + Spt[b];
        const double inter = w0 * i0 + w1 * i1;
        double dice = (2.0 * inter + 1.0) / (uni + 1.0);
        if (isnan(dice)) dice = 1.0;
        dsum += dice;
    }
    return 1.0 - 0.5 * dsum;
}

__global__ void finalize_k(const float* __restrict__ ws,
                           const float* __restrict__ calib,
                           const int* __restrict__ wt,
                           float* __restrict__ out)
{
    const int t = threadIdx.x;

    // ECE terms in parallel: lanes 0..39 each handle one (class, bin) cell.
    const unsigned int* bins = (const unsigned int*)ws + 40;
    float term = 0.0f;
    if (t < 40) {
        const int cc = t / NBINS;        // 0 -> class 1, 1 -> class 2
        const int k  = t % NBINS;
        const float bt   = fsigmoid((float)bins[cc * 40 + k]);
        const float btot = fsigmoid((float)bins[cc * 40 + 20 + k]);
        const float cal  = fsigmoid(calib[k * 4 + (cc + 1)]);
        const float d = cal - __fdividef(bt, btot);
        term = d * d;
    }
    #pragma unroll
    for (int off = 32; off > 0; off >>= 1) term += __shfl_xor(term, off, 64);

    if (t == 0) {
        const double means[4] = {0.03, 0.02, 0.01, 0.01};
        double L1 = 0.0, L2 = 0.0;
        for (int c = 0; c < 4; ++c) {
            const double mean = means[c];
            const double w1 = 1.0 / (mean * mean);
            const double w0 = 1.0 / ((1.0 - mean) * (1.0 - mean));
            double Sp[2], Spt1[2], C1[2], St2[2], Spt2[2];
            for (int b = 0; b < 2; ++b) {
                Sp[b]   = (double)ws[b * 20 + 0 + c];
                Spt1[b] = (double)ws[b * 20 + 4 + c];
                C1[b]   = (double)ws[b * 20 + 8 + c];
                St2[b]  = (double)ws[b * 20 + 12 + c];
                Spt2[b] = (double)ws[b * 20 + 16 + c];
            }
            L1 += dice_term(Sp, C1, Spt1, w0, w1);
            L2 += dice_term(Sp, St2, Spt2, w0, w1);
        }
        L1 *= 0.2; L2 *= 0.2;   // sum of 4 channel losses / 5.0
        const double w = (double)wt[0];
        const double ece = (double)term / (double)NBINS;
        out[0] = (float)(w * L1 + (1.0 - w) * L2 + ece);
    }
}

extern "C" void kernel_launch(void* const* d_in, const int* in_sizes, int n_in,
                              void* d_out, int out_size, void* d_ws, size_t ws_size,
                              hipStream_t stream)
{
    const float* seg    = (const float*)d_in[0];
    const float* calib  = (const float*)d_in[1];
    const float* logits = (const float*)d_in[2];
    const int*   y      = (const int*)d_in[3];
    const int*   wt     = (const int*)d_in[4];
    float* ws  = (float*)d_ws;
    float* out = (float*)d_out;

    hipMemsetAsync(ws, 0, WS_WORDS * sizeof(float), stream);
    hipLaunchKernelGGL(hybrid_main_k, dim3(1024), dim3(256), 0, stream,
                       seg, logits, y, wt, ws);
    hipLaunchKernelGGL(finalize_k, dim3(1), dim3(64), 0, stream, ws, calib, wt, out);
}

// Round 6
// 160.409 us; speedup vs baseline: 1.4747x; 1.0840x over previous
//
#include <hip/hip_runtime.h>
#include <math.h>

// Geometry: seg_out/logits (2,4,128,128,128) f32, y (2,1,128,128,128) i32,
// calib (20,4) f32, weight scalar int. Output: 1 f32 scalar.
#define VB 2097152            // voxels per (batch, channel) = 128^3
#define QB (VB / 4)           // float4 quads per (batch, channel)
#define NBINS 20

// 120 logical counters: [0..39] float acc[2][5][4] {Sp,Spt1,Cnt,St2,Spt2}x{ch};
//                       [40..119] uint bins[2][2][20] {cls1,cls2}x{true,total}x{bin}
// PHYSICAL layout: each counter gets 2 slots (block-parity), each slot on its
// own 128-B cache line -> device-scope atomic RMWs spread across 240 lines /
// L2 channels instead of serializing on ~4 shared lines.
#define NCNT 120
#define PADW 32                               // words per 128-B line
#define PIDX(i, s) ((((i) * 2) + (s)) * PADW) // word index of counter i, slot s
#define WS_BYTES (NCNT * 2 * PADW * 4)        // 30720 B

// Privatized LDS histogram: 8 copies, stride 81 words.
#define HCOPIES 8
#define HSTRIDE 81

__device__ __forceinline__ float sel(const float4 v, int j) {
    return j == 0 ? v.x : (j == 1 ? v.y : (j == 2 ? v.z : v.w));
}
__device__ __forceinline__ int seli(const int4 v, int j) {
    return j == 0 ? v.x : (j == 1 ? v.y : (j == 2 ? v.z : v.w));
}

__global__ __launch_bounds__(256) void hybrid_main_k(
        const float* __restrict__ seg, const float* __restrict__ logits,
        const int* __restrict__ y, const int* __restrict__ wt,
        float* __restrict__ ws)
{
    const int b   = blockIdx.x & 1;       // interleave batches across XCDs
    const int blk = blockIdx.x >> 1;      // 0..511
    const int tid = threadIdx.x;

    __shared__ unsigned int shb[HCOPIES * HSTRIDE];   // 2592 B
    __shared__ float shred[20][4];

    for (int i = tid; i < HCOPIES * HSTRIDE; i += 256) shb[i] = 0u;
    __syncthreads();

    // weight==1 => (1-w)*L2 == 0 exactly; skip the logits stream (uniform,
    // deterministic branch: inputs restored before every launch).
    const bool need2 = (wt[0] != 1);

    const float4* s0 = (const float4*)seg + (size_t)(b * 4 + 0) * QB;
    const float4* s1 = (const float4*)seg + (size_t)(b * 4 + 1) * QB;
    const float4* s2 = (const float4*)seg + (size_t)(b * 4 + 2) * QB;
    const float4* s3 = (const float4*)seg + (size_t)(b * 4 + 3) * QB;
    const float4* l0 = (const float4*)logits + (size_t)(b * 4 + 0) * QB;
    const float4* l1 = (const float4*)logits + (size_t)(b * 4 + 1) * QB;
    const float4* l2 = (const float4*)logits + (size_t)(b * 4 + 2) * QB;
    const float4* l3 = (const float4*)logits + (size_t)(b * 4 + 3) * QB;
    const int4*   yq = (const int4*)y + (size_t)b * QB;

    // acc[0..3]=Sp, [4..7]=Spt1(one-hot), [8..11]=Cnt1(as float, exact),
    // [12..15]=St2(sigmoid), [16..19]=Spt2
    float acc[20];
    #pragma unroll
    for (int k = 0; k < 20; ++k) acc[k] = 0.0f;

    const float INV_STEP = 20.0f / (1.0f + 1e-8f);  // searchsorted(linspace(0,1+1e-8,21),'right')-1
    const int hbase = (tid & (HCOPIES - 1)) * HSTRIDE;

    for (int q = blk * 256 + tid; q < QB; q += 512 * 256) {
        const int4   yv = yq[q];
        const float4 p0 = s0[q], p1 = s1[q], p2 = s2[q], p3 = s3[q];
        float4 g0 = {0,0,0,0}, g1 = {0,0,0,0}, g2 = {0,0,0,0}, g3 = {0,0,0,0};
        if (need2) { g0 = l0[q]; g1 = l1[q]; g2 = l2[q]; g3 = l3[q]; }

        #pragma unroll
        for (int j = 0; j < 4; ++j) {
            const float pv0 = sel(p0, j), pv1 = sel(p1, j), pv2 = sel(p2, j), pv3 = sel(p3, j);
            const int yj = seli(yv, j);

            acc[0] += pv0; acc[1] += pv1; acc[2] += pv2; acc[3] += pv3;
            acc[4] += (yj == 0) ? pv0 : 0.0f;
            acc[5] += (yj == 1) ? pv1 : 0.0f;
            acc[6] += (yj == 2) ? pv2 : 0.0f;
            acc[7] += (yj == 3) ? pv3 : 0.0f;
            acc[8]  += (yj == 0) ? 1.0f : 0.0f;
            acc[9]  += (yj == 1) ? 1.0f : 0.0f;
            acc[10] += (yj == 2) ? 1.0f : 0.0f;
            acc[11] += (yj == 3) ? 1.0f : 0.0f;

            if (need2) {
                const float sg0 = __fdividef(1.0f, 1.0f + __expf(-sel(g0, j)));
                const float sg1 = __fdividef(1.0f, 1.0f + __expf(-sel(g1, j)));
                const float sg2 = __fdividef(1.0f, 1.0f + __expf(-sel(g2, j)));
                const float sg3 = __fdividef(1.0f, 1.0f + __expf(-sel(g3, j)));
                acc[12] += sg0; acc[13] += sg1; acc[14] += sg2; acc[15] += sg3;
                acc[16] += pv0 * sg0; acc[17] += pv1 * sg1;
                acc[18] += pv2 * sg2; acc[19] += pv3 * sg3;
            }

            // softmax over channels (matches jax.nn.softmax: exp(x - max)/sum)
            const float mx = fmaxf(fmaxf(pv0, pv1), fmaxf(pv2, pv3));
            const float e0 = __expf(pv0 - mx), e1 = __expf(pv1 - mx);
            const float e2 = __expf(pv2 - mx), e3 = __expf(pv3 - mx);
            const float ssum = (e0 + e1) + (e2 + e3);
            const float pr1 = __fdividef(e1, ssum);
            const float pr2 = __fdividef(e2, ssum);
            int b1 = (int)(pr1 * INV_STEP); if (b1 > 19) b1 = 19;
            int b2 = (int)(pr2 * INV_STEP); if (b2 > 19) b2 = 19;
            atomicAdd(&shb[hbase + 20 + b1], 1u);   // class-1 total
            atomicAdd(&shb[hbase + 60 + b2], 1u);   // class-2 total
            if (yj == 1 || yj == 2) {               // mutually exclusive trues
                const int addr = (yj == 1) ? (hbase + b1) : (hbase + 40 + b2);
                atomicAdd(&shb[addr], 1u);
            }
        }
    }

    // wave(64) shuffle reduce each of the 20 accumulators
    #pragma unroll
    for (int k = 0; k < 20; ++k) {
        float v = acc[k];
        #pragma unroll
        for (int off = 32; off > 0; off >>= 1) v += __shfl_xor(v, off, 64);
        acc[k] = v;
    }
    const int wave = tid >> 6, lane = tid & 63;
    if (lane == 0) {
        #pragma unroll
        for (int k = 0; k < 20; ++k) shred[k][wave] = acc[k];
    }
    __syncthreads();

    // ---- padded, slot-split global accumulation ----
    const int slot = (blockIdx.x >> 1) & 1;
    const int nrows = need2 ? 20 : 12;   // rows 12..19 are exactly 0 when w==1
    if (tid < nrows) {
        float t = shred[tid][0] + shred[tid][1] + shred[tid][2] + shred[tid][3];
        atomicAdd(&ws[PIDX(b * 20 + tid, slot)], t);
    }
    if (tid < 80) {
        unsigned int v = 0;
        #pragma unroll
        for (int c = 0; c < HCOPIES; ++c) v += shb[c * HSTRIDE + tid];
        if (v) atomicAdd((unsigned int*)ws + PIDX(40 + tid, slot), v);
    }
}

__device__ __forceinline__ float fsigmoid(float x) {
    return __fdividef(1.0f, 1.0f + __expf(-x));
}

__device__ double dice_term(const double Sp[2], const double St[2], const double Spt[2],
                            double w0, double w1)
{
    const double sumP = Sp[0] + Sp[1], sumT = St[0] + St[1];
    const double u1 = sumP + sumT;
    const double u0 = (2.0 * (double)VB - sumP) + (2.0 * (double)VB - sumT);
    const double uni = w0 * u0 + w1 * u1;
    double dsum = 0.0;
    for (int b = 0; b < 2; ++b) {
        const double i1 = Spt[b];
        const double i0 = (double)VB - Sp[b] - St[b] + Spt[b];
        const double inter = w0 * i0 + w1 * i1;
        double dice = (2.0 * inter + 1.0) / (uni + 1.0);
        if (isnan(dice)) dice = 1.0;
        dsum += dice;
    }
    return 1.0 - 0.5 * dsum;
}

__device__ __forceinline__ float rd_acc(const float* ws, int i) {
    return ws[PIDX(i, 0)] + ws[PIDX(i, 1)];
}

__global__ void finalize_k(const float* __restrict__ ws,
                           const float* __restrict__ calib,
                           const int* __restrict__ wt,
                           float* __restrict__ out)
{
    const int t = threadIdx.x;
    const unsigned int* wsu = (const unsigned int*)ws;

    // ECE terms in parallel: lanes 0..39 each handle one (class, bin) cell.
    float term = 0.0f;
    if (t < 40) {
        const int cc = t / NBINS;        // 0 -> class 1, 1 -> class 2
        const int k  = t % NBINS;
        const unsigned int nt = wsu[PIDX(40 + cc * 40 + k, 0)] +
                                wsu[PIDX(40 + cc * 40 + k, 1)];
        const unsigned int nn = wsu[PIDX(40 + cc * 40 + 20 + k, 0)] +
                                wsu[PIDX(40 + cc * 40 + 20 + k, 1)];
        const float bt   = fsigmoid((float)nt);
        const float btot = fsigmoid((float)nn);
        const float cal  = fsigmoid(calib[k * 4 + (cc + 1)]);
        const float d = cal - __fdividef(bt, btot);
        term = d * d;
    }
    #pragma unroll
    for (int off = 32; off > 0; off >>= 1) term += __shfl_xor(term, off, 64);

    if (t == 0) {
        const double means[4] = {0.03, 0.02, 0.01, 0.01};
        double L1 = 0.0, L2 = 0.0;
        for (int c = 0; c < 4; ++c) {
            const double mean = means[c];
            const double w1 = 1.0 / (mean * mean);
            const double w0 = 1.0 / ((1.0 - mean) * (1.0 - mean));
            double Sp[2], Spt1[2], C1[2], St2[2], Spt2[2];
            for (int b = 0; b < 2; ++b) {
                Sp[b]   = (double)rd_acc(ws, b * 20 + 0 + c);
                Spt1[b] = (double)rd_acc(ws, b * 20 + 4 + c);
                C1[b]   = (double)rd_acc(ws, b * 20 + 8 + c);
                St2[b]  = (double)rd_acc(ws, b * 20 + 12 + c);
                Spt2[b] = (double)rd_acc(ws, b * 20 + 16 + c);
            }
            L1 += dice_term(Sp, C1, Spt1, w0, w1);
            L2 += dice_term(Sp, St2, Spt2, w0, w1);
        }
        L1 *= 0.2; L2 *= 0.2;   // sum of 4 channel losses / 5.0
        const double w = (double)wt[0];
        const double ece = (double)term / (double)NBINS;
        out[0] = (float)(w * L1 + (1.0 - w) * L2 + ece);
    }
}

extern "C" void kernel_launch(void* const* d_in, const int* in_sizes, int n_in,
                              void* d_out, int out_size, void* d_ws, size_t ws_size,
                              hipStream_t stream)
{
    const float* seg    = (const float*)d_in[0];
    const float* calib  = (const float*)d_in[1];
    const float* logits = (const float*)d_in[2];
    const int*   y      = (const int*)d_in[3];
    const int*   wt     = (const int*)d_in[4];
    float* ws  = (float*)d_ws;
    float* out = (float*)d_out;

    hipMemsetAsync(ws, 0, WS_BYTES, stream);
    hipLaunchKernelGGL(hybrid_main_k, dim3(1024), dim3(256), 0, stream,
                       seg, logits, y, wt, ws);
    hipLaunchKernelGGL(finalize_k, dim3(1), dim3(64), 0, stream, ws, calib, wt, out);
}

// Round 7
// 160.154 us; speedup vs baseline: 1.4770x; 1.0016x over previous
//
#include <hip/hip_runtime.h>
#include <math.h>

// Geometry: seg_out/logits (2,4,128,128,128) f32, y (2,1,128,128,128) i32,
// calib (20,4) f32, weight scalar int. Output: 1 f32 scalar.
#define VB 2097152            // voxels per (batch, channel) = 128^3
#define QB (VB / 4)           // float4 quads per (batch, channel)
#define NBINS 20

// Accumulation layout (proven R6 win): every global counter lives on its own
// 128-B cache line, x2 slots by block parity -> device-scope atomic RMWs
// spread across many L2 lines instead of serializing on ~4 shared lines.
//   words [0 .. 80*PADW)            : 40 float accs (2 batches x 20 rows) x2 slots
//   words [HBASEW .. HBASEW+80*PADW): 40 u64 hist counters {true<<32|total} x2 slots
#define PADW 32                                // words per 128-B line
#define PIDX(i, s) ((((i) * 2) + (s)) * PADW)  // word offset of acc i, slot s
#define HBASEW (80 * PADW)
#define WS_BYTES (160 * PADW * 4)              // 20480 B

// Privatized LDS histogram: 8 copies, stride 81 words (81%32 odd => distinct banks).
#define HCOPIES 8
#define HSTRIDE 81

#define NBLK 1024
#define BPB 512
#define QSTRIDE (BPB * 256)    // 131072; KITER * QSTRIDE == QB
#define KITER 4

__device__ __forceinline__ float sel(const float4 v, int j) {
    return j == 0 ? v.x : (j == 1 ? v.y : (j == 2 ? v.z : v.w));
}
__device__ __forceinline__ int seli(const int4 v, int j) {
    return j == 0 ? v.x : (j == 1 ? v.y : (j == 2 ? v.z : v.w));
}

__global__ void hybrid_main_k(
        const float* __restrict__ seg, const float* __restrict__ logits,
        const int* __restrict__ y, const int* __restrict__ wt,
        float* __restrict__ ws)
{
    const int b   = blockIdx.x & 1;       // interleave batches across XCDs
    const int blk = blockIdx.x >> 1;      // 0..511
    const int tid = threadIdx.x;

    __shared__ unsigned int shb[HCOPIES * HSTRIDE];   // 2592 B
    __shared__ float shred[20][4];

    for (int i = tid; i < HCOPIES * HSTRIDE; i += 256) shb[i] = 0u;
    __syncthreads();

    // weight==1 => (1-w)*L2 == 0 exactly; skip the logits stream (uniform,
    // deterministic branch: inputs restored before every launch).
    const bool need2 = (wt[0] != 1);

    const float4* s0 = (const float4*)seg + (size_t)(b * 4 + 0) * QB;
    const float4* s1 = (const float4*)seg + (size_t)(b * 4 + 1) * QB;
    const float4* s2 = (const float4*)seg + (size_t)(b * 4 + 2) * QB;
    const float4* s3 = (const float4*)seg + (size_t)(b * 4 + 3) * QB;
    const int4*   yq = (const int4*)y + (size_t)b * QB;

    // acc[0..3]=Sp, [4..7]=Spt1(one-hot), [8..11]=Cnt1(as float, exact),
    // [12..15]=St2(sigmoid), [16..19]=Spt2
    float acc[20];
    #pragma unroll
    for (int k = 0; k < 20; ++k) acc[k] = 0.0f;

    const float INV_STEP = 20.0f / (1.0f + 1e-8f);
    const int hbase = (tid & (HCOPIES - 1)) * HSTRIDE;
    const int q0 = blk * 256 + tid;

    // ---- software-pipelined loop: prefetch tile k+1 while computing k ----
    float4 cP0 = s0[q0], cP1 = s1[q0], cP2 = s2[q0], cP3 = s3[q0];
    int4   cY  = yq[q0];

    #pragma unroll
    for (int k = 0; k < KITER; ++k) {
        float4 nP0, nP1, nP2, nP3; int4 nY;
        if (k + 1 < KITER) {
            const int q = q0 + (k + 1) * QSTRIDE;
            nP0 = s0[q]; nP1 = s1[q]; nP2 = s2[q]; nP3 = s3[q]; nY = yq[q];
        }
        float4 G0, G1, G2, G3;
        if (need2) {
            const float4* l0 = (const float4*)logits + (size_t)(b * 4 + 0) * QB;
            const float4* l1 = (const float4*)logits + (size_t)(b * 4 + 1) * QB;
            const float4* l2 = (const float4*)logits + (size_t)(b * 4 + 2) * QB;
            const float4* l3 = (const float4*)logits + (size_t)(b * 4 + 3) * QB;
            const int q = q0 + k * QSTRIDE;
            G0 = l0[q]; G1 = l1[q]; G2 = l2[q]; G3 = l3[q];
        }

        #pragma unroll
        for (int j = 0; j < 4; ++j) {
            const float pv0 = sel(cP0, j), pv1 = sel(cP1, j);
            const float pv2 = sel(cP2, j), pv3 = sel(cP3, j);
            const int yj = seli(cY, j);

            acc[0] += pv0; acc[1] += pv1; acc[2] += pv2; acc[3] += pv3;
            acc[4] += (yj == 0) ? pv0 : 0.0f;
            acc[5] += (yj == 1) ? pv1 : 0.0f;
            acc[6] += (yj == 2) ? pv2 : 0.0f;
            acc[7] += (yj == 3) ? pv3 : 0.0f;
            acc[8]  += (yj == 0) ? 1.0f : 0.0f;
            acc[9]  += (yj == 1) ? 1.0f : 0.0f;
            acc[10] += (yj == 2) ? 1.0f : 0.0f;
            acc[11] += (yj == 3) ? 1.0f : 0.0f;

            if (need2) {
                const float sg0 = __fdividef(1.0f, 1.0f + __expf(-sel(G0, j)));
                const float sg1 = __fdividef(1.0f, 1.0f + __expf(-sel(G1, j)));
                const float sg2 = __fdividef(1.0f, 1.0f + __expf(-sel(G2, j)));
                const float sg3 = __fdividef(1.0f, 1.0f + __expf(-sel(G3, j)));
                acc[12] += sg0; acc[13] += sg1; acc[14] += sg2; acc[15] += sg3;
                acc[16] += pv0 * sg0; acc[17] += pv1 * sg1;
                acc[18] += pv2 * sg2; acc[19] += pv3 * sg3;
            }

            // softmax over channels (matches jax.nn.softmax: exp(x-max)/sum)
            const float mx = fmaxf(fmaxf(pv0, pv1), fmaxf(pv2, pv3));
            const float e0 = __expf(pv0 - mx), e1 = __expf(pv1 - mx);
            const float e2 = __expf(pv2 - mx), e3 = __expf(pv3 - mx);
            const float ssum = (e0 + e1) + (e2 + e3);
            const float pr1 = __fdividef(e1, ssum);
            const float pr2 = __fdividef(e2, ssum);
            int b1 = (int)(pr1 * INV_STEP); if (b1 > 19) b1 = 19;
            int b2 = (int)(pr2 * INV_STEP); if (b2 > 19) b2 = 19;
            atomicAdd(&shb[hbase + 20 + b1], 1u);   // class-1 total
            atomicAdd(&shb[hbase + 60 + b2], 1u);   // class-2 total
            if (yj == 1 || yj == 2) {               // mutually exclusive trues
                const int addr = (yj == 1) ? (hbase + b1) : (hbase + 40 + b2);
                atomicAdd(&shb[addr], 1u);
            }
        }
        cP0 = nP0; cP1 = nP1; cP2 = nP2; cP3 = nP3; cY = nY;
    }

    // ---- block reduction ----
    #pragma unroll
    for (int k = 0; k < 20; ++k) {
        float v = acc[k];
        #pragma unroll
        for (int off = 32; off > 0; off >>= 1) v += __shfl_xor(v, off, 64);
        acc[k] = v;
    }
    const int wave = tid >> 6, lane = tid & 63;
    if (lane == 0) {
        #pragma unroll
        for (int k = 0; k < 20; ++k) shred[k][wave] = acc[k];
    }
    __syncthreads();

    // ---- padded, slot-split global accumulation ----
    const int slot = (blockIdx.x >> 1) & 1;
    const int nrows = need2 ? 20 : 12;   // rows 12..19 stay 0 when w==1
    if (tid < nrows) {
        float t = shred[tid][0] + shred[tid][1] + shred[tid][2] + shred[tid][3];
        atomicAdd(&ws[PIDX(b * 20 + tid, slot)], t);
    }
    // histogram: pack {true, total} for one (class, bin) into one u64 atomic.
    if (tid < 40) {
        const int cc = tid / 20, k = tid % 20;
        unsigned int vt = 0, vn = 0;
        #pragma unroll
        for (int c = 0; c < HCOPIES; ++c) {
            vt += shb[c * HSTRIDE + cc * 40 + k];
            vn += shb[c * HSTRIDE + cc * 40 + 20 + k];
        }
        const unsigned long long pk = ((unsigned long long)vt << 32) | vn;
        if (pk) {
            unsigned long long* h =
                (unsigned long long*)(ws + HBASEW) + (size_t)(tid * 2 + slot) * (PADW / 2);
            atomicAdd(h, pk);
        }
    }
}

__device__ __forceinline__ float fsigmoid(float x) {
    return __fdividef(1.0f, 1.0f + __expf(-x));
}

__device__ double dice_term(const double Sp[2], const double St[2], const double Spt[2],
                            double w0, double w1)
{
    const double sumP = Sp[0] + Sp[1], sumT = St[0] + St[1];
    const double u1 = sumP + sumT;
    const double u0 = (2.0 * (double)VB - sumP) + (2.0 * (double)VB - sumT);
    const double uni = w0 * u0 + w1 * u1;
    double dsum = 0.0;
    for (int b = 0; b < 2; ++b) {
        const double i1 = Spt[b];
        const double i0 = (double)VB - Sp[b] - St[b] + Spt[b];
        const double inter = w0 * i0 + w1 * i1;
        double dice = (2.0 * inter + 1.0) / (uni + 1.0);
        if (isnan(dice)) dice = 1.0;
        dsum += dice;
    }
    return 1.0 - 0.5 * dsum;
}

__device__ __forceinline__ float rd_acc(const float* ws, int i) {
    return ws[PIDX(i, 0)] + ws[PIDX(i, 1)];
}

__global__ void finalize_k(const float* __restrict__ ws,
                           const float* __restrict__ calib,
                           const int* __restrict__ wt,
                           float* __restrict__ out)
{
    const int t = threadIdx.x;

    // ECE terms in parallel: lanes 0..39 each handle one (class, bin) cell.
    float term = 0.0f;
    if (t < 40) {
        const unsigned long long* h = (const unsigned long long*)(ws + HBASEW);
        const unsigned long long v = h[(size_t)(t * 2 + 0) * (PADW / 2)] +
                                     h[(size_t)(t * 2 + 1) * (PADW / 2)];
        const unsigned int vt = (unsigned int)(v >> 32);
        const unsigned int vn = (unsigned int)v;
        const int cc = t / NBINS, k = t % NBINS;
        const float bt   = fsigmoid((float)vt);
        const float btot = fsigmoid((float)vn);
        const float cal  = fsigmoid(calib[k * 4 + (cc + 1)]);
        const float d = cal - __fdividef(bt, btot);
        term = d * d;
    }
    #pragma unroll
    for (int off = 32; off > 0; off >>= 1) term += __shfl_xor(term, off, 64);

    if (t == 0) {
        const double means[4] = {0.03, 0.02, 0.01, 0.01};
        double L1 = 0.0, L2 = 0.0;
        for (int c = 0; c < 4; ++c) {
            const double mean = means[c];
            const double w1 = 1.0 / (mean * mean);
            const double w0 = 1.0 / ((1.0 - mean) * (1.0 - mean));
            double Sp[2], Spt1[2], C1[2], St2[2], Spt2[2];
            for (int b = 0; b < 2; ++b) {
                Sp[b]   = (double)rd_acc(ws, b * 20 + 0 + c);
                Spt1[b] = (double)rd_acc(ws, b * 20 + 4 + c);
                C1[b]   = (double)rd_acc(ws, b * 20 + 8 + c);
                St2[b]  = (double)rd_acc(ws, b * 20 + 12 + c);
                Spt2[b] = (double)rd_acc(ws, b * 20 + 16 + c);
            }
            L1 += dice_term(Sp, C1, Spt1, w0, w1);
            L2 += dice_term(Sp, St2, Spt2, w0, w1);
        }
        L1 *= 0.2; L2 *= 0.2;   // sum of 4 channel losses / 5.0
        const double w = (double)wt[0];
        const double ece = (double)term / (double)NBINS;
        out[0] = (float)(w * L1 + (1.0 - w) * L2 + ece);
    }
}

extern "C" void kernel_launch(void* const* d_in, const int* in_sizes, int n_in,
                              void* d_out, int out_size, void* d_ws, size_t ws_size,
                              hipStream_t stream)
{
    const float* seg    = (const float*)d_in[0];
    const float* calib  = (const float*)d_in[1];
    const float* logits = (const float*)d_in[2];
    const int*   y      = (const int*)d_in[3];
    const int*   wt     = (const int*)d_in[4];
    float* ws  = (float*)d_ws;
    float* out = (float*)d_out;

    hipMemsetAsync(ws, 0, WS_BYTES, stream);
    hipLaunchKernelGGL(hybrid_main_k, dim3(NBLK), dim3(256), 0, stream,
                       seg, logits, y, wt, ws);
    hipLaunchKernelGGL(finalize_k, dim3(1), dim3(64), 0, stream, ws, calib, wt, out);
}